// Round 11
// baseline (82.668 us; speedup 1.0000x reference)
//
#include <hip/hip_runtime.h>
#include <math.h>

namespace {

constexpr int NA = 120;
constexpr int LR = 128;
constexpr int LZ = 192;
constexpr int UW2 = 182;          // u' rows 0..181 (u' = i0 + 27, i0 in [-27,154])
constexpr int ZSTR = UW2 * 16;    // 2912 B per zb step
constexpr int ASTR = 24 * ZSTR;   // 69888 B per angle slab
constexpr float CTR = 63.5f;      // unpadded-space center

typedef float v2f __attribute__((ext_vector_type(2)));

__device__ inline void pk_fma(v2f& acc, v2f w, v2f t) {
    asm("v_pk_fma_f32 %0, %1, %2, %0" : "+v"(acc) : "v"(w), "v"(t));
}

// ============ pre-pass: zb-major fp8 PAIR buffer ============================
// Entry (a, zb, u') = 16 B: interleaved fp8 pairs (row u'-27, row u'-26) for
// z in [8*zb, 8*zb+8), values stored centered (v - 0.5). Out-of-range rows
// (zero-pad region) store fp8(-0.5) -> no masks in the main loop:
// w*(v-0.5) + 0.5*w == w*v holds for v==0 margins too.
__global__ __launch_bounds__(256) void cvt9(const float* __restrict__ img,
                                            unsigned char* __restrict__ pb) {
    const int idx = blockIdx.x * 256 + threadIdx.x;
    if (idx >= NA * UW2 * 24) return; // 524,160
    const int up = idx % UW2;         // u' fast -> coalesced 16B writes
    const int t  = idx / UW2;
    const int zb = t % 24;
    const int a  = t / 24;
    const int z0 = zb * 8;
    const int r0 = up - 27;
    const int r1 = up - 26;

    float v0[8], v1[8];
    if (r0 >= 0 && r0 < LR) {
        const float4* p = reinterpret_cast<const float4*>(img + (a * LR + r0) * LZ + z0);
        const float4 x = p[0], y = p[1];
        v0[0]=x.x; v0[1]=x.y; v0[2]=x.z; v0[3]=x.w;
        v0[4]=y.x; v0[5]=y.y; v0[6]=y.z; v0[7]=y.w;
    } else {
#pragma unroll
        for (int j = 0; j < 8; ++j) v0[j] = 0.f;
    }
    if (r1 >= 0 && r1 < LR) {
        const float4* p = reinterpret_cast<const float4*>(img + (a * LR + r1) * LZ + z0);
        const float4 x = p[0], y = p[1];
        v1[0]=x.x; v1[1]=x.y; v1[2]=x.z; v1[3]=x.w;
        v1[4]=y.x; v1[5]=y.y; v1[6]=y.z; v1[7]=y.w;
    } else {
#pragma unroll
        for (int j = 0; j < 8; ++j) v1[j] = 0.f;
    }

    uint4 o;
    unsigned* od = &o.x;
#pragma unroll
    for (int d = 0; d < 4; ++d) {
        int w = __builtin_amdgcn_cvt_pk_fp8_f32(v0[2*d]   - 0.5f, v1[2*d]   - 0.5f, 0, false);
        w = __builtin_amdgcn_cvt_pk_fp8_f32(v0[2*d+1] - 0.5f, v1[2*d+1] - 0.5f, w, true);
        od[d] = (unsigned)w;
    }
    *reinterpret_cast<uint4*>(pb + ((size_t)a * ASTR + (size_t)zb * ZSTR + (size_t)up * 16)) = o;
}

// ============ main: 4096 blocks (z-halved), 27 waves/CU, ring-4 =============
struct __align__(8) G11 {
    float w0;       // weight of row i0; w1 = 1 - w0 (exact, so sum(w) == 120)
    unsigned boff;  // t*ASTR + (i0+27)*16
};

__global__ __launch_bounds__(192, 8) void bp_v11(const unsigned char* __restrict__ pb,
                                                 float* __restrict__ out) {
    __shared__ float2 s_cs[NA];
    __shared__ G11 s_geo[NA + 4][16]; // rows 120..123: prefetch-only pads

    const int tid = threadIdx.x; // 0..191

    if (tid < NA) {
        const float ang = (float)tid * (float)(2.0 * M_PI / (double)NA);
        const float phi = (float)(1.5 * M_PI) - ang;
        s_cs[tid] = make_float2(cosf(phi), sinf(phi));
    }
    __syncthreads();

    // 4096 blocks; XCD-aware chunked swizzle (bijective: 4096 % 8 == 0)
    const int bid = blockIdx.x;
    const int swz = (bid & 7) * 512 + (bid >> 3);
    const int y  = swz >> 5;              // 0..127
    const int xg = ((swz >> 1) & 7) << 4; // x base, step 16
    const int zh = swz & 1;               // z half (zb 0..11 or 12..23)

    const float Y = (float)y - CTR;
    for (int e = tid; e < 16 * (NA + 4); e += 192) {
        const int p = e & 15;
        const int t = e >> 4;
        G11 g;
        if (t < NA) {
            const float2 cs = s_cs[t];
            const float X = (float)(xg + p) - CTR;
            const float u  = fmaf(cs.y, Y, fmaf(cs.x, X, CTR));
            const float fl = floorf(u);
            g.w0   = 1.0f - (u - fl);
            g.boff = (unsigned)(t * ASTR + ((int)fl + 27) * 16);
        } else {
            g.w0 = 0.f; g.boff = 0; // pad: prefetched, never blended
        }
        s_geo[t][p] = g;
    }
    __syncthreads();

    const int px = tid & 15;        // 16-px clusters -> ~4 lines per cluster
    const int zo = tid >> 4;        // 0..11
    const unsigned zbase = (unsigned)((zh * 12 + zo) * ZSTR);

    v2f acc[8]; // acc[j] = (sum w0*t0, sum w1*t1) for local z = j
#pragma unroll
    for (int j = 0; j < 8; ++j) acc[j] = (v2f){0.f, 0.f};

    // depth-4 ring (branch-free; pads prefetched only)
    float wr[4];
    uint4 T[4];
#pragma unroll
    for (int k = 0; k < 4; ++k) {
        const G11 g = s_geo[k][px];
        wr[k] = g.w0;
        T[k] = *reinterpret_cast<const uint4*>(pb + (g.boff + zbase));
    }

    for (int t0 = 0; t0 < NA; t0 += 4) {
#pragma unroll
        for (int k = 0; k < 4; ++k) {
            const uint4 cur = T[k];
            const float cw0 = wr[k];
            const G11 g = s_geo[t0 + k + 4][px];
            wr[k] = g.w0;
            T[k] = *reinterpret_cast<const uint4*>(pb + (g.boff + zbase));
            const v2f cw = {cw0, 1.0f - cw0};
            const unsigned* q = &cur.x;
#pragma unroll
            for (int d = 0; d < 4; ++d) {
                const v2f lo = __builtin_amdgcn_cvt_pk_f32_fp8((int)q[d], false); // (t0,t1) z=2d
                const v2f hi = __builtin_amdgcn_cvt_pk_f32_fp8((int)q[d], true);  // (t0,t1) z=2d+1
                pk_fma(acc[2*d + 0], cw, lo);
                pk_fma(acc[2*d + 1], cw, hi);
            }
        }
    }

    // out = (acc + 0.5 * sum(w)) / (120 + 1e-11); sum(w) == 120 exactly
    const float inv = (float)(1.0 / (120.0 + 1e-11));
    float* op = out + (size_t)(y * LR + xg + px) * LZ + (zh * 12 + zo) * 8;
    float4 r0, r1;
    r0.x = (acc[0][0] + acc[0][1] + 60.0f) * inv;
    r0.y = (acc[1][0] + acc[1][1] + 60.0f) * inv;
    r0.z = (acc[2][0] + acc[2][1] + 60.0f) * inv;
    r0.w = (acc[3][0] + acc[3][1] + 60.0f) * inv;
    r1.x = (acc[4][0] + acc[4][1] + 60.0f) * inv;
    r1.y = (acc[5][0] + acc[5][1] + 60.0f) * inv;
    r1.z = (acc[6][0] + acc[6][1] + 60.0f) * inv;
    r1.w = (acc[7][0] + acc[7][1] + 60.0f) * inv;
    *reinterpret_cast<float4*>(op)     = r0;
    *reinterpret_cast<float4*>(op + 4) = r1;
}

// ============ v5 fallback (smaller workspace): fp8 taps, 8 z/lane ===========
struct __align__(16) Geo {
    float w0, w1;
    int b0, b1;
};

__global__ __launch_bounds__(256) void cvt_fp8(const float* __restrict__ in,
                                               unsigned int* __restrict__ out8,
                                               int n16) {
    const int i = blockIdx.x * 256 + threadIdx.x;
    if (i >= n16) return;
    const float4* p = reinterpret_cast<const float4*>(in) + (size_t)i * 4;
    uint4 o;
    unsigned int* od = &o.x;
#pragma unroll
    for (int d = 0; d < 4; ++d) {
        const float4 f = p[d];
        int w = __builtin_amdgcn_cvt_pk_fp8_f32(f.x - 0.5f, f.y - 0.5f, 0, false);
        w = __builtin_amdgcn_cvt_pk_fp8_f32(f.z - 0.5f, f.w - 0.5f, w, true);
        od[d] = (unsigned int)w;
    }
    reinterpret_cast<uint4*>(out8)[i] = o;
}

__device__ inline void blend8(v2f acc[4], float w0, float w1,
                              const uint2& t0, const uint2& t1) {
    const v2f W0 = {w0, w0};
    const v2f W1 = {w1, w1};
    const unsigned int* q0 = &t0.x;
    const unsigned int* q1 = &t1.x;
#pragma unroll
    for (int d = 0; d < 2; ++d) {
        const v2f a_lo = __builtin_amdgcn_cvt_pk_f32_fp8((int)q0[d], false);
        const v2f a_hi = __builtin_amdgcn_cvt_pk_f32_fp8((int)q0[d], true);
        const v2f b_lo = __builtin_amdgcn_cvt_pk_f32_fp8((int)q1[d], false);
        const v2f b_hi = __builtin_amdgcn_cvt_pk_f32_fp8((int)q1[d], true);
        acc[2 * d + 0] = acc[2 * d + 0] + W0 * a_lo + W1 * b_lo;
        acc[2 * d + 1] = acc[2 * d + 1] + W0 * a_hi + W1 * b_hi;
    }
}

__global__ __launch_bounds__(192, 6) void bp_v5(const unsigned char* __restrict__ img,
                                                float* __restrict__ out) {
    __shared__ float2 s_cs[NA];
    __shared__ Geo s_geo[NA][8];
    __shared__ float s_sumw[8];

    const int tid = threadIdx.x;
    if (tid < NA) {
        const float ang = (float)tid * (float)(2.0 * M_PI / (double)NA);
        const float phi = (float)(1.5 * M_PI) - ang;
        s_cs[tid] = make_float2(cosf(phi), sinf(phi));
    }
    __syncthreads();

    const int bid = blockIdx.x;
    const int swz = (bid & 7) * 256 + (bid >> 3);
    const int y  = swz >> 4;
    const int xg = (swz & 15) << 3;

    const float Y = (float)y - CTR;
    for (int e = tid; e < 8 * NA; e += 192) {
        const int p = e & 7;
        const int a = e >> 3;
        const float2 cs = s_cs[a];
        const float X = (float)(xg + p) - CTR;
        const float u  = fmaf(cs.y, Y, fmaf(cs.x, X, CTR));
        const float fl = floorf(u);
        const float wx = u - fl;
        const int i0 = (int)fl;
        Geo g;
        g.w0 = ((unsigned)i0 < 128u) ? (1.0f - wx) : 0.0f;
        g.w1 = ((unsigned)(i0 + 1) < 128u) ? wx : 0.0f;
        const int o0 = min(max(i0, 0), LR - 1);
        const int o1 = min(max(i0 + 1, 0), LR - 1);
        g.b0 = (a * LR + o0) * LZ;
        g.b1 = (a * LR + o1) * LZ;
        s_geo[a][p] = g;
    }
    __syncthreads();

    if (tid < 8) {
        float s = 0.f;
        for (int a = 0; a < NA; ++a) s += s_geo[a][tid].w0 + s_geo[a][tid].w1;
        s_sumw[tid] = s;
    }
    __syncthreads();

    const int zo = tid % 24;
    const int px = tid / 24;
    const unsigned char* base = img + zo * 8;

    v2f acc[4];
#pragma unroll
    for (int j = 0; j < 4; ++j) acc[j] = (v2f){0.f, 0.f};

    Geo ga = s_geo[0][px];
    Geo gb = s_geo[1][px];
    uint2 A0 = *reinterpret_cast<const uint2*>(base + ga.b0);
    uint2 A1 = *reinterpret_cast<const uint2*>(base + ga.b1);
    uint2 B0 = *reinterpret_cast<const uint2*>(base + gb.b0);
    uint2 B1 = *reinterpret_cast<const uint2*>(base + gb.b1);

    for (int a = 0; a < NA - 2; a += 2) {
        const Geo gn = s_geo[a + 2][px];
        const uint2 N0 = *reinterpret_cast<const uint2*>(base + gn.b0);
        const uint2 N1 = *reinterpret_cast<const uint2*>(base + gn.b1);
        blend8(acc, ga.w0, ga.w1, A0, A1);
        ga = gn; A0 = N0; A1 = N1;
        const Geo gm = s_geo[a + 3][px];
        const uint2 M0 = *reinterpret_cast<const uint2*>(base + gm.b0);
        const uint2 M1 = *reinterpret_cast<const uint2*>(base + gm.b1);
        blend8(acc, gb.w0, gb.w1, B0, B1);
        gb = gm; B0 = M0; B1 = M1;
    }
    blend8(acc, ga.w0, ga.w1, A0, A1);
    blend8(acc, gb.w0, gb.w1, B0, B1);

    const float inv = (float)(1.0 / (120.0 + 1e-11));
    const float half_sw = 0.5f * s_sumw[px];
    float* op = out + ((size_t)(y * LR + xg + px)) * LZ + zo * 8;
    float4 r0, r1;
    r0.x = (acc[0][0] + half_sw) * inv;
    r0.y = (acc[0][1] + half_sw) * inv;
    r0.z = (acc[1][0] + half_sw) * inv;
    r0.w = (acc[1][1] + half_sw) * inv;
    r1.x = (acc[2][0] + half_sw) * inv;
    r1.y = (acc[2][1] + half_sw) * inv;
    r1.z = (acc[3][0] + half_sw) * inv;
    r1.w = (acc[3][1] + half_sw) * inv;
    *reinterpret_cast<float4*>(op)     = r0;
    *reinterpret_cast<float4*>(op + 4) = r1;
}

// ============ fp32 fallback (no workspace) ==================================
__global__ __launch_bounds__(192) void bp_main(const float* __restrict__ img,
                                               float* __restrict__ out) {
    __shared__ float s_cp[NA];
    __shared__ float s_sp[NA];
    struct __align__(16) GeoF { float w0, w1; int off0, off1; };
    __shared__ GeoF s_geo[4][NA];

    const int tx = threadIdx.x;
    const int py = threadIdx.y;
    const int tid = py * 48 + tx;
    const int y  = blockIdx.x >> 5;
    const int xg = (blockIdx.x & 31) << 2;

    if (tid < NA) {
        const float ang = (float)tid * (float)(2.0 * M_PI / (double)NA);
        const float phi = (float)(1.5 * M_PI) - ang;
        s_cp[tid] = cosf(phi);
        s_sp[tid] = sinf(phi);
    }
    __syncthreads();

    for (int e = tid; e < 4 * NA; e += 192) {
        const int a = e % NA;
        const int p = e / NA;
        const float cp = s_cp[a];
        const float sp = s_sp[a];
        const float Yf = (float)y - CTR;
        const float Xf = (float)(xg + p) - CTR;
        const float u = sp * Yf + cp * Xf + CTR;
        const float fl = floorf(u);
        const float wx = u - fl;
        const int i0 = (int)fl;
        GeoF g;
        g.w0 = (i0 >= 0 && i0 < LR) ? (1.0f - wx) : 0.0f;
        g.w1 = (i0 >= -1 && i0 < LR - 1) ? wx : 0.0f;
        const int o0 = min(max(i0, 0), LR - 1);
        const int o1 = min(max(i0 + 1, 0), LR - 1);
        g.off0 = (a * LR + o0) * LZ;
        g.off1 = (a * LR + o1) * LZ;
        s_geo[p][a] = g;
    }
    __syncthreads();

    const int zb = tx << 2;
    float4 acc = make_float4(0.f, 0.f, 0.f, 0.f);
#pragma unroll 4
    for (int a = 0; a < NA; ++a) {
        const GeoF g = s_geo[py][a];
        const float4 v0 = *reinterpret_cast<const float4*>(img + g.off0 + zb);
        const float4 v1 = *reinterpret_cast<const float4*>(img + g.off1 + zb);
        acc.x = fmaf(g.w0, v0.x, fmaf(g.w1, v1.x, acc.x));
        acc.y = fmaf(g.w0, v0.y, fmaf(g.w1, v1.y, acc.y));
        acc.z = fmaf(g.w0, v0.z, fmaf(g.w1, v1.z, acc.z));
        acc.w = fmaf(g.w0, v0.w, fmaf(g.w1, v1.w, acc.w));
    }
    const float inv = (float)(1.0 / (120.0 + 1e-11));
    float4 r;
    r.x = acc.x * inv; r.y = acc.y * inv; r.z = acc.z * inv; r.w = acc.w * inv;
    *reinterpret_cast<float4*>(out + (y * LR + xg + py) * LZ + zb) = r;
}

} // namespace

extern "C" void kernel_launch(void* const* d_in, const int* in_sizes, int n_in,
                              void* d_out, int out_size, void* d_ws, size_t ws_size,
                              hipStream_t stream) {
    const float* img = (const float*)d_in[0];
    float* out = (float*)d_out;
    const int n = NA * LR * LZ;                        // 2,949,120
    const size_t v11_bytes = (size_t)NA * ASTR;        // 8,386,560
    const size_t fp8_bytes = (size_t)n;                // 2,949,120

    if (ws_size >= v11_bytes) {
        unsigned char* pb = (unsigned char*)d_ws;
        const int nt = NA * UW2 * 24;                  // 524,160
        hipLaunchKernelGGL(cvt9, dim3((nt + 255) / 256), dim3(256), 0, stream,
                           img, pb);
        hipLaunchKernelGGL(bp_v11, dim3(4096), dim3(192), 0, stream, pb, out);
    } else if (ws_size >= fp8_bytes) {
        unsigned int* img8 = (unsigned int*)d_ws;
        const int n16 = n / 16;
        hipLaunchKernelGGL(cvt_fp8, dim3((n16 + 255) / 256), dim3(256), 0, stream,
                           img, img8, n16);
        hipLaunchKernelGGL(bp_v5, dim3(128 * 16), dim3(192), 0, stream,
                           (const unsigned char*)img8, out);
    } else {
        hipLaunchKernelGGL(bp_main, dim3(128 * 32), dim3(48, 4), 0, stream,
                           img, out);
    }
}

// Round 12
// 57.842 us; speedup vs baseline: 1.4292x; 1.4292x over previous
//
#include <hip/hip_runtime.h>
#include <math.h>

namespace {

constexpr int NA = 120;
constexpr int LR = 128;
constexpr int LZ = 192;
constexpr int UW2 = 182;          // u' rows 0..181 (u' = i0 + 27, i0 in [-27,154])
constexpr int ZSTR = UW2 * 16;    // 2912 B per zb step
constexpr int ASTR = 24 * ZSTR;   // 69888 B per angle slab
constexpr float CTR = 63.5f;      // unpadded-space center

typedef float v2f __attribute__((ext_vector_type(2)));

__device__ inline void pk_fma(v2f& acc, v2f w, v2f t) {
    asm("v_pk_fma_f32 %0, %1, %2, %0" : "+v"(acc) : "v"(w), "v"(t));
}

// ============ pre-pass: zb-major fp8 PAIR buffer ============================
// Entry (a, zb, u') = 16 B: interleaved fp8 pairs (row u'-27, row u'-26) for
// z in [8*zb, 8*zb+8), values stored centered (v - 0.5). Out-of-range rows
// (zero-pad region) store fp8(-0.5) -> no masks in the main loop:
// w*(v-0.5) + 0.5*w == w*v holds for v==0 margins too.
__global__ __launch_bounds__(256) void cvt9(const float* __restrict__ img,
                                            unsigned char* __restrict__ pb) {
    const int idx = blockIdx.x * 256 + threadIdx.x;
    if (idx >= NA * UW2 * 24) return; // 524,160
    const int up = idx % UW2;         // u' fast -> coalesced 16B writes
    const int t  = idx / UW2;
    const int zb = t % 24;
    const int a  = t / 24;
    const int z0 = zb * 8;
    const int r0 = up - 27;
    const int r1 = up - 26;

    float v0[8], v1[8];
    if (r0 >= 0 && r0 < LR) {
        const float4* p = reinterpret_cast<const float4*>(img + (a * LR + r0) * LZ + z0);
        const float4 x = p[0], y = p[1];
        v0[0]=x.x; v0[1]=x.y; v0[2]=x.z; v0[3]=x.w;
        v0[4]=y.x; v0[5]=y.y; v0[6]=y.z; v0[7]=y.w;
    } else {
#pragma unroll
        for (int j = 0; j < 8; ++j) v0[j] = 0.f;
    }
    if (r1 >= 0 && r1 < LR) {
        const float4* p = reinterpret_cast<const float4*>(img + (a * LR + r1) * LZ + z0);
        const float4 x = p[0], y = p[1];
        v1[0]=x.x; v1[1]=x.y; v1[2]=x.z; v1[3]=x.w;
        v1[4]=y.x; v1[5]=y.y; v1[6]=y.z; v1[7]=y.w;
    } else {
#pragma unroll
        for (int j = 0; j < 8; ++j) v1[j] = 0.f;
    }

    uint4 o;
    unsigned* od = &o.x;
#pragma unroll
    for (int d = 0; d < 4; ++d) {
        int w = __builtin_amdgcn_cvt_pk_fp8_f32(v0[2*d]   - 0.5f, v1[2*d]   - 0.5f, 0, false);
        w = __builtin_amdgcn_cvt_pk_fp8_f32(v0[2*d+1] - 0.5f, v1[2*d+1] - 0.5f, w, true);
        od[d] = (unsigned)w;
    }
    *reinterpret_cast<uint4*>(pb + ((size_t)a * ASTR + (size_t)zb * ZSTR + (size_t)up * 16)) = o;
}

// ============ main: 8 px x 24 zo, 2048 blocks, 24 waves/CU, ring-4 ==========
struct __align__(8) G12 {
    float w0;       // weight of row i0; w1 = 1 - w0 (exact, so sum(w) == 120)
    unsigned boff;  // t*ASTR + (i0+27)*16
};

__global__ __launch_bounds__(192, 8) void bp_v12(const unsigned char* __restrict__ pb,
                                                 float* __restrict__ out) {
    __shared__ float2 s_cs[NA];
    __shared__ G12 s_geo[NA + 4][8]; // rows 120..123: prefetch-only pads (~8.9KB)

    const int tid = threadIdx.x; // 0..191

    if (tid < NA) {
        const float ang = (float)tid * (float)(2.0 * M_PI / (double)NA);
        const float phi = (float)(1.5 * M_PI) - ang;
        s_cs[tid] = make_float2(cosf(phi), sinf(phi));
    }
    __syncthreads();

    // 2048 blocks; XCD-aware chunked swizzle (bijective: 2048 % 8 == 0)
    const int bid = blockIdx.x;
    const int swz = (bid & 7) * 256 + (bid >> 3); // bits 0..10, all consumed
    const int y  = swz >> 4;        // 0..127  (bits 4..10)
    const int xg = (swz & 15) << 3; // x base, step 8 (bits 0..3)

    const float Y = (float)y - CTR;
    for (int e = tid; e < 8 * (NA + 4); e += 192) {
        const int p = e & 7;
        const int t = e >> 3;
        G12 g;
        if (t < NA) {
            const float2 cs = s_cs[t];
            const float X = (float)(xg + p) - CTR;
            const float u  = fmaf(cs.y, Y, fmaf(cs.x, X, CTR));
            const float fl = floorf(u);
            g.w0   = 1.0f - (u - fl);
            g.boff = (unsigned)(t * ASTR + ((int)fl + 27) * 16);
        } else {
            g.w0 = 0.f; g.boff = 0; // pad: prefetched, never blended
        }
        s_geo[t][p] = g;
    }
    __syncthreads();

    const int px = tid & 7;   // 8-px clusters: ~2-3 cache lines per cluster
    const int zo = tid >> 3;  // 0..23
    const unsigned zbase = (unsigned)(zo * ZSTR);

    v2f acc[8]; // acc[j] = (sum w0*t0, sum w1*t1) for local z = j
#pragma unroll
    for (int j = 0; j < 8; ++j) acc[j] = (v2f){0.f, 0.f};

    // depth-4 ring (branch-free; pads prefetched only)
    float wr[4];
    uint4 T[4];
#pragma unroll
    for (int k = 0; k < 4; ++k) {
        const G12 g = s_geo[k][px];
        wr[k] = g.w0;
        T[k] = *reinterpret_cast<const uint4*>(pb + (g.boff + zbase));
    }

    for (int t0 = 0; t0 < NA; t0 += 4) {
#pragma unroll
        for (int k = 0; k < 4; ++k) {
            const uint4 cur = T[k];
            const float cw0 = wr[k];
            const G12 g = s_geo[t0 + k + 4][px];
            wr[k] = g.w0;
            T[k] = *reinterpret_cast<const uint4*>(pb + (g.boff + zbase));
            const v2f cw = {cw0, 1.0f - cw0};
            const unsigned* q = &cur.x;
#pragma unroll
            for (int d = 0; d < 4; ++d) {
                const v2f lo = __builtin_amdgcn_cvt_pk_f32_fp8((int)q[d], false); // (t0,t1) z=2d
                const v2f hi = __builtin_amdgcn_cvt_pk_f32_fp8((int)q[d], true);  // (t0,t1) z=2d+1
                pk_fma(acc[2*d + 0], cw, lo);
                pk_fma(acc[2*d + 1], cw, hi);
            }
        }
    }

    // out = (acc + 0.5 * sum(w)) / (120 + 1e-11); sum(w) == 120 exactly
    const float inv = (float)(1.0 / (120.0 + 1e-11));
    float* op = out + (size_t)(y * LR + xg + px) * LZ + zo * 8;
    float4 r0, r1;
    r0.x = (acc[0][0] + acc[0][1] + 60.0f) * inv;
    r0.y = (acc[1][0] + acc[1][1] + 60.0f) * inv;
    r0.z = (acc[2][0] + acc[2][1] + 60.0f) * inv;
    r0.w = (acc[3][0] + acc[3][1] + 60.0f) * inv;
    r1.x = (acc[4][0] + acc[4][1] + 60.0f) * inv;
    r1.y = (acc[5][0] + acc[5][1] + 60.0f) * inv;
    r1.z = (acc[6][0] + acc[6][1] + 60.0f) * inv;
    r1.w = (acc[7][0] + acc[7][1] + 60.0f) * inv;
    *reinterpret_cast<float4*>(op)     = r0;
    *reinterpret_cast<float4*>(op + 4) = r1;
}

// ============ v5 fallback (smaller workspace): fp8 taps, 8 z/lane ===========
struct __align__(16) Geo {
    float w0, w1;
    int b0, b1;
};

__global__ __launch_bounds__(256) void cvt_fp8(const float* __restrict__ in,
                                               unsigned int* __restrict__ out8,
                                               int n16) {
    const int i = blockIdx.x * 256 + threadIdx.x;
    if (i >= n16) return;
    const float4* p = reinterpret_cast<const float4*>(in) + (size_t)i * 4;
    uint4 o;
    unsigned int* od = &o.x;
#pragma unroll
    for (int d = 0; d < 4; ++d) {
        const float4 f = p[d];
        int w = __builtin_amdgcn_cvt_pk_fp8_f32(f.x - 0.5f, f.y - 0.5f, 0, false);
        w = __builtin_amdgcn_cvt_pk_fp8_f32(f.z - 0.5f, f.w - 0.5f, w, true);
        od[d] = (unsigned int)w;
    }
    reinterpret_cast<uint4*>(out8)[i] = o;
}

__device__ inline void blend8(v2f acc[4], float w0, float w1,
                              const uint2& t0, const uint2& t1) {
    const v2f W0 = {w0, w0};
    const v2f W1 = {w1, w1};
    const unsigned int* q0 = &t0.x;
    const unsigned int* q1 = &t1.x;
#pragma unroll
    for (int d = 0; d < 2; ++d) {
        const v2f a_lo = __builtin_amdgcn_cvt_pk_f32_fp8((int)q0[d], false);
        const v2f a_hi = __builtin_amdgcn_cvt_pk_f32_fp8((int)q0[d], true);
        const v2f b_lo = __builtin_amdgcn_cvt_pk_f32_fp8((int)q1[d], false);
        const v2f b_hi = __builtin_amdgcn_cvt_pk_f32_fp8((int)q1[d], true);
        acc[2 * d + 0] = acc[2 * d + 0] + W0 * a_lo + W1 * b_lo;
        acc[2 * d + 1] = acc[2 * d + 1] + W0 * a_hi + W1 * b_hi;
    }
}

__global__ __launch_bounds__(192, 6) void bp_v5(const unsigned char* __restrict__ img,
                                                float* __restrict__ out) {
    __shared__ float2 s_cs[NA];
    __shared__ Geo s_geo[NA][8];
    __shared__ float s_sumw[8];

    const int tid = threadIdx.x;
    if (tid < NA) {
        const float ang = (float)tid * (float)(2.0 * M_PI / (double)NA);
        const float phi = (float)(1.5 * M_PI) - ang;
        s_cs[tid] = make_float2(cosf(phi), sinf(phi));
    }
    __syncthreads();

    const int bid = blockIdx.x;
    const int swz = (bid & 7) * 256 + (bid >> 3);
    const int y  = swz >> 4;
    const int xg = (swz & 15) << 3;

    const float Y = (float)y - CTR;
    for (int e = tid; e < 8 * NA; e += 192) {
        const int p = e & 7;
        const int a = e >> 3;
        const float2 cs = s_cs[a];
        const float X = (float)(xg + p) - CTR;
        const float u  = fmaf(cs.y, Y, fmaf(cs.x, X, CTR));
        const float fl = floorf(u);
        const float wx = u - fl;
        const int i0 = (int)fl;
        Geo g;
        g.w0 = ((unsigned)i0 < 128u) ? (1.0f - wx) : 0.0f;
        g.w1 = ((unsigned)(i0 + 1) < 128u) ? wx : 0.0f;
        const int o0 = min(max(i0, 0), LR - 1);
        const int o1 = min(max(i0 + 1, 0), LR - 1);
        g.b0 = (a * LR + o0) * LZ;
        g.b1 = (a * LR + o1) * LZ;
        s_geo[a][p] = g;
    }
    __syncthreads();

    if (tid < 8) {
        float s = 0.f;
        for (int a = 0; a < NA; ++a) s += s_geo[a][tid].w0 + s_geo[a][tid].w1;
        s_sumw[tid] = s;
    }
    __syncthreads();

    const int zo = tid % 24;
    const int px = tid / 24;
    const unsigned char* base = img + zo * 8;

    v2f acc[4];
#pragma unroll
    for (int j = 0; j < 4; ++j) acc[j] = (v2f){0.f, 0.f};

    Geo ga = s_geo[0][px];
    Geo gb = s_geo[1][px];
    uint2 A0 = *reinterpret_cast<const uint2*>(base + ga.b0);
    uint2 A1 = *reinterpret_cast<const uint2*>(base + ga.b1);
    uint2 B0 = *reinterpret_cast<const uint2*>(base + gb.b0);
    uint2 B1 = *reinterpret_cast<const uint2*>(base + gb.b1);

    for (int a = 0; a < NA - 2; a += 2) {
        const Geo gn = s_geo[a + 2][px];
        const uint2 N0 = *reinterpret_cast<const uint2*>(base + gn.b0);
        const uint2 N1 = *reinterpret_cast<const uint2*>(base + gn.b1);
        blend8(acc, ga.w0, ga.w1, A0, A1);
        ga = gn; A0 = N0; A1 = N1;
        const Geo gm = s_geo[a + 3][px];
        const uint2 M0 = *reinterpret_cast<const uint2*>(base + gm.b0);
        const uint2 M1 = *reinterpret_cast<const uint2*>(base + gm.b1);
        blend8(acc, gb.w0, gb.w1, B0, B1);
        gb = gm; B0 = M0; B1 = M1;
    }
    blend8(acc, ga.w0, ga.w1, A0, A1);
    blend8(acc, gb.w0, gb.w1, B0, B1);

    const float inv = (float)(1.0 / (120.0 + 1e-11));
    const float half_sw = 0.5f * s_sumw[px];
    float* op = out + ((size_t)(y * LR + xg + px)) * LZ + zo * 8;
    float4 r0, r1;
    r0.x = (acc[0][0] + half_sw) * inv;
    r0.y = (acc[0][1] + half_sw) * inv;
    r0.z = (acc[1][0] + half_sw) * inv;
    r0.w = (acc[1][1] + half_sw) * inv;
    r1.x = (acc[2][0] + half_sw) * inv;
    r1.y = (acc[2][1] + half_sw) * inv;
    r1.z = (acc[3][0] + half_sw) * inv;
    r1.w = (acc[3][1] + half_sw) * inv;
    *reinterpret_cast<float4*>(op)     = r0;
    *reinterpret_cast<float4*>(op + 4) = r1;
}

// ============ fp32 fallback (no workspace) ==================================
__global__ __launch_bounds__(192) void bp_main(const float* __restrict__ img,
                                               float* __restrict__ out) {
    __shared__ float s_cp[NA];
    __shared__ float s_sp[NA];
    struct __align__(16) GeoF { float w0, w1; int off0, off1; };
    __shared__ GeoF s_geo[4][NA];

    const int tx = threadIdx.x;
    const int py = threadIdx.y;
    const int tid = py * 48 + tx;
    const int y  = blockIdx.x >> 5;
    const int xg = (blockIdx.x & 31) << 2;

    if (tid < NA) {
        const float ang = (float)tid * (float)(2.0 * M_PI / (double)NA);
        const float phi = (float)(1.5 * M_PI) - ang;
        s_cp[tid] = cosf(phi);
        s_sp[tid] = sinf(phi);
    }
    __syncthreads();

    for (int e = tid; e < 4 * NA; e += 192) {
        const int a = e % NA;
        const int p = e / NA;
        const float cp = s_cp[a];
        const float sp = s_sp[a];
        const float Yf = (float)y - CTR;
        const float Xf = (float)(xg + p) - CTR;
        const float u = sp * Yf + cp * Xf + CTR;
        const float fl = floorf(u);
        const float wx = u - fl;
        const int i0 = (int)fl;
        GeoF g;
        g.w0 = (i0 >= 0 && i0 < LR) ? (1.0f - wx) : 0.0f;
        g.w1 = (i0 >= -1 && i0 < LR - 1) ? wx : 0.0f;
        const int o0 = min(max(i0, 0), LR - 1);
        const int o1 = min(max(i0 + 1, 0), LR - 1);
        g.off0 = (a * LR + o0) * LZ;
        g.off1 = (a * LR + o1) * LZ;
        s_geo[p][a] = g;
    }
    __syncthreads();

    const int zb = tx << 2;
    float4 acc = make_float4(0.f, 0.f, 0.f, 0.f);
#pragma unroll 4
    for (int a = 0; a < NA; ++a) {
        const GeoF g = s_geo[py][a];
        const float4 v0 = *reinterpret_cast<const float4*>(img + g.off0 + zb);
        const float4 v1 = *reinterpret_cast<const float4*>(img + g.off1 + zb);
        acc.x = fmaf(g.w0, v0.x, fmaf(g.w1, v1.x, acc.x));
        acc.y = fmaf(g.w0, v0.y, fmaf(g.w1, v1.y, acc.y));
        acc.z = fmaf(g.w0, v0.z, fmaf(g.w1, v1.z, acc.z));
        acc.w = fmaf(g.w0, v0.w, fmaf(g.w1, v1.w, acc.w));
    }
    const float inv = (float)(1.0 / (120.0 + 1e-11));
    float4 r;
    r.x = acc.x * inv; r.y = acc.y * inv; r.z = acc.z * inv; r.w = acc.w * inv;
    *reinterpret_cast<float4*>(out + (y * LR + xg + py) * LZ + zb) = r;
}

} // namespace

extern "C" void kernel_launch(void* const* d_in, const int* in_sizes, int n_in,
                              void* d_out, int out_size, void* d_ws, size_t ws_size,
                              hipStream_t stream) {
    const float* img = (const float*)d_in[0];
    float* out = (float*)d_out;
    const int n = NA * LR * LZ;                        // 2,949,120
    const size_t v12_bytes = (size_t)NA * ASTR;        // 8,386,560
    const size_t fp8_bytes = (size_t)n;                // 2,949,120

    if (ws_size >= v12_bytes) {
        unsigned char* pb = (unsigned char*)d_ws;
        const int nt = NA * UW2 * 24;                  // 524,160
        hipLaunchKernelGGL(cvt9, dim3((nt + 255) / 256), dim3(256), 0, stream,
                           img, pb);
        hipLaunchKernelGGL(bp_v12, dim3(2048), dim3(192), 0, stream, pb, out);
    } else if (ws_size >= fp8_bytes) {
        unsigned int* img8 = (unsigned int*)d_ws;
        const int n16 = n / 16;
        hipLaunchKernelGGL(cvt_fp8, dim3((n16 + 255) / 256), dim3(256), 0, stream,
                           img, img8, n16);
        hipLaunchKernelGGL(bp_v5, dim3(128 * 16), dim3(192), 0, stream,
                           (const unsigned char*)img8, out);
    } else {
        hipLaunchKernelGGL(bp_main, dim3(128 * 32), dim3(48, 4), 0, stream,
                           img, out);
    }
}

// Round 13
// 50.576 us; speedup vs baseline: 1.6345x; 1.1437x over previous
//
#include <hip/hip_runtime.h>
#include <math.h>

namespace {

constexpr int NA = 120;
constexpr int LR = 128;
constexpr int LZ = 192;
constexpr int UW2 = 182;          // u' rows 0..181 (u' = i0 + 27, i0 in [-27,154])
constexpr int ZSTR = UW2 * 16;    // 2912 B per zb step
constexpr int ASTR = 24 * ZSTR;   // 69888 B per angle slab
constexpr float CTR = 63.5f;      // unpadded-space center

typedef float v2f __attribute__((ext_vector_type(2)));
typedef _Float16 half_t;
typedef half_t v2h __attribute__((ext_vector_type(2)));

#if defined(__has_builtin)
#if __has_builtin(__builtin_amdgcn_cvt_pk_f16_fp8) && __has_builtin(__builtin_amdgcn_fdot2)
#define USE_F16_DOT 1
#endif
#endif

__device__ inline void pk_fma(v2f& acc, v2f w, v2f t) {
    asm("v_pk_fma_f32 %0, %1, %2, %0" : "+v"(acc) : "v"(w), "v"(t));
}

// ============ pre-pass: zb-major fp8 PAIR buffer ============================
// Entry (a, zb, u') = 16 B: interleaved fp8 pairs (row u'-27, row u'-26) for
// z in [8*zb, 8*zb+8), values stored centered (v - 0.5). Out-of-range rows
// (zero-pad region) store fp8(-0.5) -> no masks in the main loop:
// w*(v-0.5) + 0.5*w == w*v holds for v==0 margins too.
__global__ __launch_bounds__(256) void cvt9(const float* __restrict__ img,
                                            unsigned char* __restrict__ pb) {
    const int idx = blockIdx.x * 256 + threadIdx.x;
    if (idx >= NA * UW2 * 24) return; // 524,160
    const int up = idx % UW2;         // u' fast -> coalesced 16B writes
    const int t  = idx / UW2;
    const int zb = t % 24;
    const int a  = t / 24;
    const int z0 = zb * 8;
    const int r0 = up - 27;
    const int r1 = up - 26;

    float v0[8], v1[8];
    if (r0 >= 0 && r0 < LR) {
        const float4* p = reinterpret_cast<const float4*>(img + (a * LR + r0) * LZ + z0);
        const float4 x = p[0], y = p[1];
        v0[0]=x.x; v0[1]=x.y; v0[2]=x.z; v0[3]=x.w;
        v0[4]=y.x; v0[5]=y.y; v0[6]=y.z; v0[7]=y.w;
    } else {
#pragma unroll
        for (int j = 0; j < 8; ++j) v0[j] = 0.f;
    }
    if (r1 >= 0 && r1 < LR) {
        const float4* p = reinterpret_cast<const float4*>(img + (a * LR + r1) * LZ + z0);
        const float4 x = p[0], y = p[1];
        v1[0]=x.x; v1[1]=x.y; v1[2]=x.z; v1[3]=x.w;
        v1[4]=y.x; v1[5]=y.y; v1[6]=y.z; v1[7]=y.w;
    } else {
#pragma unroll
        for (int j = 0; j < 8; ++j) v1[j] = 0.f;
    }

    uint4 o;
    unsigned* od = &o.x;
#pragma unroll
    for (int d = 0; d < 4; ++d) {
        int w = __builtin_amdgcn_cvt_pk_fp8_f32(v0[2*d]   - 0.5f, v1[2*d]   - 0.5f, 0, false);
        w = __builtin_amdgcn_cvt_pk_fp8_f32(v0[2*d+1] - 0.5f, v1[2*d+1] - 0.5f, w, true);
        od[d] = (unsigned)w;
    }
    *reinterpret_cast<uint4*>(pb + ((size_t)a * ASTR + (size_t)zb * ZSTR + (size_t)up * 16)) = o;
}

// ============ main: v10 config + f16 dot2 blend =============================
struct __align__(8) G13 {
    unsigned w;     // f16 path: packed half2 (w0,w1); f32 path: bits of w0
    unsigned boff;  // t*ASTR + (i0+27)*16
};

__global__ __launch_bounds__(384, 6) void bp_v13(const unsigned char* __restrict__ pb,
                                                 float* __restrict__ out) {
    __shared__ float2 s_cs[NA];
    __shared__ G13 s_geo[NA + 4][16]; // rows 120..123: prefetch-only pads

    const int tid = threadIdx.x; // 0..383

    if (tid < NA) {
        const float ang = (float)tid * (float)(2.0 * M_PI / (double)NA);
        const float phi = (float)(1.5 * M_PI) - ang;
        s_cs[tid] = make_float2(cosf(phi), sinf(phi));
    }
    __syncthreads();

    // 1024 blocks; XCD-aware chunked swizzle (bijective: 1024 % 8 == 0)
    const int bid = blockIdx.x;
    const int swz = (bid & 7) * 128 + (bid >> 3);
    const int y  = swz >> 3;        // 0..127
    const int xg = (swz & 7) << 4;  // x base, step 16

    const float Y = (float)y - CTR;
    for (int e = tid; e < 16 * (NA + 4); e += 384) {
        const int p = e & 15;
        const int t = e >> 4;
        G13 g;
        if (t < NA) {
            const float2 cs = s_cs[t];
            const float X = (float)(xg + p) - CTR;
            const float u  = fmaf(cs.y, Y, fmaf(cs.x, X, CTR));
            const float fl = floorf(u);
            const float wx = u - fl;
#ifdef USE_F16_DOT
            union { v2h h; unsigned u32; } cw;
            cw.h = (v2h){(half_t)(1.0f - wx), (half_t)wx};
            g.w = cw.u32;
#else
            g.w = __float_as_uint(1.0f - wx);
#endif
            g.boff = (unsigned)(t * ASTR + ((int)fl + 27) * 16);
        } else {
            g.w = 0u; g.boff = 0; // pad: prefetched, never blended (w==0)
        }
        s_geo[t][p] = g;
    }
    __syncthreads();

    const int px = tid & 15;        // px-fast: 16-lane clusters read adjacent u
    const int zo = tid >> 4;        // 0..23
    const unsigned zbase = (unsigned)(zo * ZSTR);

#ifdef USE_F16_DOT
    float fac[8];
#pragma unroll
    for (int j = 0; j < 8; ++j) fac[j] = 0.f;
#else
    v2f acc[8];
#pragma unroll
    for (int j = 0; j < 8; ++j) acc[j] = (v2f){0.f, 0.f};
#endif

    // depth-4 ring (branch-free; pads prefetched only)
    unsigned wr[4];
    uint4 T[4];
#pragma unroll
    for (int k = 0; k < 4; ++k) {
        const G13 g = s_geo[k][px];
        wr[k] = g.w;
        T[k] = *reinterpret_cast<const uint4*>(pb + (g.boff + zbase));
    }

    for (int t0 = 0; t0 < NA; t0 += 4) {
#pragma unroll
        for (int k = 0; k < 4; ++k) {
            const uint4 cur = T[k];
            const unsigned cwb = wr[k];
            const G13 g = s_geo[t0 + k + 4][px];
            wr[k] = g.w;
            T[k] = *reinterpret_cast<const uint4*>(pb + (g.boff + zbase));
            const unsigned* q = &cur.x;
#ifdef USE_F16_DOT
            union { unsigned u32; v2h h; } cw;
            cw.u32 = cwb;
#pragma unroll
            for (int d = 0; d < 4; ++d) {
                // dword d bytes: (t0 z=2d, t1 z=2d, t0 z=2d+1, t1 z=2d+1)
                const v2h lo = __builtin_amdgcn_cvt_pk_f16_fp8((short)(q[d] & 0xffffu));
                const v2h hi = __builtin_amdgcn_cvt_pk_f16_fp8((short)(q[d] >> 16));
                fac[2*d + 0] = __builtin_amdgcn_fdot2(cw.h, lo, fac[2*d + 0], false);
                fac[2*d + 1] = __builtin_amdgcn_fdot2(cw.h, hi, fac[2*d + 1], false);
            }
#else
            const float cw0 = __uint_as_float(cwb);
            const v2f cw = {cw0, 1.0f - cw0};
#pragma unroll
            for (int d = 0; d < 4; ++d) {
                const v2f lo = __builtin_amdgcn_cvt_pk_f32_fp8((int)q[d], false);
                const v2f hi = __builtin_amdgcn_cvt_pk_f32_fp8((int)q[d], true);
                pk_fma(acc[2*d + 0], cw, lo);
                pk_fma(acc[2*d + 1], cw, hi);
            }
#endif
        }
    }

    // out = (acc + 0.5 * sum(w)) / (120 + 1e-11); sum(w) == 120 (w1 = 1-w0)
    const float inv = (float)(1.0 / (120.0 + 1e-11));
    float* op = out + (size_t)(y * LR + xg + px) * LZ + zo * 8;
    float4 r0, r1;
#ifdef USE_F16_DOT
    r0.x = (fac[0] + 60.0f) * inv;
    r0.y = (fac[1] + 60.0f) * inv;
    r0.z = (fac[2] + 60.0f) * inv;
    r0.w = (fac[3] + 60.0f) * inv;
    r1.x = (fac[4] + 60.0f) * inv;
    r1.y = (fac[5] + 60.0f) * inv;
    r1.z = (fac[6] + 60.0f) * inv;
    r1.w = (fac[7] + 60.0f) * inv;
#else
    r0.x = (acc[0][0] + acc[0][1] + 60.0f) * inv;
    r0.y = (acc[1][0] + acc[1][1] + 60.0f) * inv;
    r0.z = (acc[2][0] + acc[2][1] + 60.0f) * inv;
    r0.w = (acc[3][0] + acc[3][1] + 60.0f) * inv;
    r1.x = (acc[4][0] + acc[4][1] + 60.0f) * inv;
    r1.y = (acc[5][0] + acc[5][1] + 60.0f) * inv;
    r1.z = (acc[6][0] + acc[6][1] + 60.0f) * inv;
    r1.w = (acc[7][0] + acc[7][1] + 60.0f) * inv;
#endif
    *reinterpret_cast<float4*>(op)     = r0;
    *reinterpret_cast<float4*>(op + 4) = r1;
}

// ============ v5 fallback (smaller workspace): fp8 taps, 8 z/lane ===========
struct __align__(16) Geo {
    float w0, w1;
    int b0, b1;
};

__global__ __launch_bounds__(256) void cvt_fp8(const float* __restrict__ in,
                                               unsigned int* __restrict__ out8,
                                               int n16) {
    const int i = blockIdx.x * 256 + threadIdx.x;
    if (i >= n16) return;
    const float4* p = reinterpret_cast<const float4*>(in) + (size_t)i * 4;
    uint4 o;
    unsigned int* od = &o.x;
#pragma unroll
    for (int d = 0; d < 4; ++d) {
        const float4 f = p[d];
        int w = __builtin_amdgcn_cvt_pk_fp8_f32(f.x - 0.5f, f.y - 0.5f, 0, false);
        w = __builtin_amdgcn_cvt_pk_fp8_f32(f.z - 0.5f, f.w - 0.5f, w, true);
        od[d] = (unsigned int)w;
    }
    reinterpret_cast<uint4*>(out8)[i] = o;
}

__device__ inline void blend8(v2f acc[4], float w0, float w1,
                              const uint2& t0, const uint2& t1) {
    const v2f W0 = {w0, w0};
    const v2f W1 = {w1, w1};
    const unsigned int* q0 = &t0.x;
    const unsigned int* q1 = &t1.x;
#pragma unroll
    for (int d = 0; d < 2; ++d) {
        const v2f a_lo = __builtin_amdgcn_cvt_pk_f32_fp8((int)q0[d], false);
        const v2f a_hi = __builtin_amdgcn_cvt_pk_f32_fp8((int)q0[d], true);
        const v2f b_lo = __builtin_amdgcn_cvt_pk_f32_fp8((int)q1[d], false);
        const v2f b_hi = __builtin_amdgcn_cvt_pk_f32_fp8((int)q1[d], true);
        acc[2 * d + 0] = acc[2 * d + 0] + W0 * a_lo + W1 * b_lo;
        acc[2 * d + 1] = acc[2 * d + 1] + W0 * a_hi + W1 * b_hi;
    }
}

__global__ __launch_bounds__(192, 6) void bp_v5(const unsigned char* __restrict__ img,
                                                float* __restrict__ out) {
    __shared__ float2 s_cs[NA];
    __shared__ Geo s_geo[NA][8];
    __shared__ float s_sumw[8];

    const int tid = threadIdx.x;
    if (tid < NA) {
        const float ang = (float)tid * (float)(2.0 * M_PI / (double)NA);
        const float phi = (float)(1.5 * M_PI) - ang;
        s_cs[tid] = make_float2(cosf(phi), sinf(phi));
    }
    __syncthreads();

    const int bid = blockIdx.x;
    const int swz = (bid & 7) * 256 + (bid >> 3);
    const int y  = swz >> 4;
    const int xg = (swz & 15) << 3;

    const float Y = (float)y - CTR;
    for (int e = tid; e < 8 * NA; e += 192) {
        const int p = e & 7;
        const int a = e >> 3;
        const float2 cs = s_cs[a];
        const float X = (float)(xg + p) - CTR;
        const float u  = fmaf(cs.y, Y, fmaf(cs.x, X, CTR));
        const float fl = floorf(u);
        const float wx = u - fl;
        const int i0 = (int)fl;
        Geo g;
        g.w0 = ((unsigned)i0 < 128u) ? (1.0f - wx) : 0.0f;
        g.w1 = ((unsigned)(i0 + 1) < 128u) ? wx : 0.0f;
        const int o0 = min(max(i0, 0), LR - 1);
        const int o1 = min(max(i0 + 1, 0), LR - 1);
        g.b0 = (a * LR + o0) * LZ;
        g.b1 = (a * LR + o1) * LZ;
        s_geo[a][p] = g;
    }
    __syncthreads();

    if (tid < 8) {
        float s = 0.f;
        for (int a = 0; a < NA; ++a) s += s_geo[a][tid].w0 + s_geo[a][tid].w1;
        s_sumw[tid] = s;
    }
    __syncthreads();

    const int zo = tid % 24;
    const int px = tid / 24;
    const unsigned char* base = img + zo * 8;

    v2f acc[4];
#pragma unroll
    for (int j = 0; j < 4; ++j) acc[j] = (v2f){0.f, 0.f};

    Geo ga = s_geo[0][px];
    Geo gb = s_geo[1][px];
    uint2 A0 = *reinterpret_cast<const uint2*>(base + ga.b0);
    uint2 A1 = *reinterpret_cast<const uint2*>(base + ga.b1);
    uint2 B0 = *reinterpret_cast<const uint2*>(base + gb.b0);
    uint2 B1 = *reinterpret_cast<const uint2*>(base + gb.b1);

    for (int a = 0; a < NA - 2; a += 2) {
        const Geo gn = s_geo[a + 2][px];
        const uint2 N0 = *reinterpret_cast<const uint2*>(base + gn.b0);
        const uint2 N1 = *reinterpret_cast<const uint2*>(base + gn.b1);
        blend8(acc, ga.w0, ga.w1, A0, A1);
        ga = gn; A0 = N0; A1 = N1;
        const Geo gm = s_geo[a + 3][px];
        const uint2 M0 = *reinterpret_cast<const uint2*>(base + gm.b0);
        const uint2 M1 = *reinterpret_cast<const uint2*>(base + gm.b1);
        blend8(acc, gb.w0, gb.w1, B0, B1);
        gb = gm; B0 = M0; B1 = M1;
    }
    blend8(acc, ga.w0, ga.w1, A0, A1);
    blend8(acc, gb.w0, gb.w1, B0, B1);

    const float inv = (float)(1.0 / (120.0 + 1e-11));
    const float half_sw = 0.5f * s_sumw[px];
    float* op = out + ((size_t)(y * LR + xg + px)) * LZ + zo * 8;
    float4 r0, r1;
    r0.x = (acc[0][0] + half_sw) * inv;
    r0.y = (acc[0][1] + half_sw) * inv;
    r0.z = (acc[1][0] + half_sw) * inv;
    r0.w = (acc[1][1] + half_sw) * inv;
    r1.x = (acc[2][0] + half_sw) * inv;
    r1.y = (acc[2][1] + half_sw) * inv;
    r1.z = (acc[3][0] + half_sw) * inv;
    r1.w = (acc[3][1] + half_sw) * inv;
    *reinterpret_cast<float4*>(op)     = r0;
    *reinterpret_cast<float4*>(op + 4) = r1;
}

// ============ fp32 fallback (no workspace) ==================================
__global__ __launch_bounds__(192) void bp_main(const float* __restrict__ img,
                                               float* __restrict__ out) {
    __shared__ float s_cp[NA];
    __shared__ float s_sp[NA];
    struct __align__(16) GeoF { float w0, w1; int off0, off1; };
    __shared__ GeoF s_geo[4][NA];

    const int tx = threadIdx.x;
    const int py = threadIdx.y;
    const int tid = py * 48 + tx;
    const int y  = blockIdx.x >> 5;
    const int xg = (blockIdx.x & 31) << 2;

    if (tid < NA) {
        const float ang = (float)tid * (float)(2.0 * M_PI / (double)NA);
        const float phi = (float)(1.5 * M_PI) - ang;
        s_cp[tid] = cosf(phi);
        s_sp[tid] = sinf(phi);
    }
    __syncthreads();

    for (int e = tid; e < 4 * NA; e += 192) {
        const int a = e % NA;
        const int p = e / NA;
        const float cp = s_cp[a];
        const float sp = s_sp[a];
        const float Yf = (float)y - CTR;
        const float Xf = (float)(xg + p) - CTR;
        const float u = sp * Yf + cp * Xf + CTR;
        const float fl = floorf(u);
        const float wx = u - fl;
        const int i0 = (int)fl;
        GeoF g;
        g.w0 = (i0 >= 0 && i0 < LR) ? (1.0f - wx) : 0.0f;
        g.w1 = (i0 >= -1 && i0 < LR - 1) ? wx : 0.0f;
        const int o0 = min(max(i0, 0), LR - 1);
        const int o1 = min(max(i0 + 1, 0), LR - 1);
        g.off0 = (a * LR + o0) * LZ;
        g.off1 = (a * LR + o1) * LZ;
        s_geo[p][a] = g;
    }
    __syncthreads();

    const int zb = tx << 2;
    float4 acc = make_float4(0.f, 0.f, 0.f, 0.f);
#pragma unroll 4
    for (int a = 0; a < NA; ++a) {
        const GeoF g = s_geo[py][a];
        const float4 v0 = *reinterpret_cast<const float4*>(img + g.off0 + zb);
        const float4 v1 = *reinterpret_cast<const float4*>(img + g.off1 + zb);
        acc.x = fmaf(g.w0, v0.x, fmaf(g.w1, v1.x, acc.x));
        acc.y = fmaf(g.w0, v0.y, fmaf(g.w1, v1.y, acc.y));
        acc.z = fmaf(g.w0, v0.z, fmaf(g.w1, v1.z, acc.z));
        acc.w = fmaf(g.w0, v0.w, fmaf(g.w1, v1.w, acc.w));
    }
    const float inv = (float)(1.0 / (120.0 + 1e-11));
    float4 r;
    r.x = acc.x * inv; r.y = acc.y * inv; r.z = acc.z * inv; r.w = acc.w * inv;
    *reinterpret_cast<float4*>(out + (y * LR + xg + py) * LZ + zb) = r;
}

} // namespace

extern "C" void kernel_launch(void* const* d_in, const int* in_sizes, int n_in,
                              void* d_out, int out_size, void* d_ws, size_t ws_size,
                              hipStream_t stream) {
    const float* img = (const float*)d_in[0];
    float* out = (float*)d_out;
    const int n = NA * LR * LZ;                        // 2,949,120
    const size_t v13_bytes = (size_t)NA * ASTR;        // 8,386,560
    const size_t fp8_bytes = (size_t)n;                // 2,949,120

    if (ws_size >= v13_bytes) {
        unsigned char* pb = (unsigned char*)d_ws;
        const int nt = NA * UW2 * 24;                  // 524,160
        hipLaunchKernelGGL(cvt9, dim3((nt + 255) / 256), dim3(256), 0, stream,
                           img, pb);
        hipLaunchKernelGGL(bp_v13, dim3(1024), dim3(384), 0, stream, pb, out);
    } else if (ws_size >= fp8_bytes) {
        unsigned int* img8 = (unsigned int*)d_ws;
        const int n16 = n / 16;
        hipLaunchKernelGGL(cvt_fp8, dim3((n16 + 255) / 256), dim3(256), 0, stream,
                           img, img8, n16);
        hipLaunchKernelGGL(bp_v5, dim3(128 * 16), dim3(192), 0, stream,
                           (const unsigned char*)img8, out);
    } else {
        hipLaunchKernelGGL(bp_main, dim3(128 * 32), dim3(48, 4), 0, stream,
                           img, out);
    }
}

// Round 14
// 49.644 us; speedup vs baseline: 1.6652x; 1.0188x over previous
//
#include <hip/hip_runtime.h>
#include <math.h>

namespace {

constexpr int NA = 120;
constexpr int LR = 128;
constexpr int LZ = 192;
constexpr int UW2 = 182;          // u' rows 0..181 (u' = i0 + 27, i0 in [-27,154])
constexpr int ZSTR = UW2 * 16;    // 2912 B per zb step
constexpr int ASTR = 24 * ZSTR;   // 69888 B per angle slab
constexpr float CTR = 63.5f;      // unpadded-space center

typedef float v2f __attribute__((ext_vector_type(2)));

__device__ inline void pk_fma(v2f& acc, v2f w, v2f t) {
    asm("v_pk_fma_f32 %0, %1, %2, %0" : "+v"(acc) : "v"(w), "v"(t));
}

// ============ pre-pass: zb-major fp8 PAIR buffer ============================
// Entry (a, zb, u') = 16 B: interleaved fp8 pairs (row u'-27, row u'-26) for
// z in [8*zb, 8*zb+8), values stored centered (v - 0.5). Out-of-range rows
// (zero-pad region) store fp8(-0.5) -> no masks in the main loop.
__global__ __launch_bounds__(256) void cvt9(const float* __restrict__ img,
                                            unsigned char* __restrict__ pb) {
    const int idx = blockIdx.x * 256 + threadIdx.x;
    if (idx >= NA * UW2 * 24) return; // 524,160
    const int up = idx % UW2;
    const int t  = idx / UW2;
    const int zb = t % 24;
    const int a  = t / 24;
    const int z0 = zb * 8;
    const int r0 = up - 27;
    const int r1 = up - 26;

    float v0[8], v1[8];
    if (r0 >= 0 && r0 < LR) {
        const float4* p = reinterpret_cast<const float4*>(img + (a * LR + r0) * LZ + z0);
        const float4 x = p[0], y = p[1];
        v0[0]=x.x; v0[1]=x.y; v0[2]=x.z; v0[3]=x.w;
        v0[4]=y.x; v0[5]=y.y; v0[6]=y.z; v0[7]=y.w;
    } else {
#pragma unroll
        for (int j = 0; j < 8; ++j) v0[j] = 0.f;
    }
    if (r1 >= 0 && r1 < LR) {
        const float4* p = reinterpret_cast<const float4*>(img + (a * LR + r1) * LZ + z0);
        const float4 x = p[0], y = p[1];
        v1[0]=x.x; v1[1]=x.y; v1[2]=x.z; v1[3]=x.w;
        v1[4]=y.x; v1[5]=y.y; v1[6]=y.z; v1[7]=y.w;
    } else {
#pragma unroll
        for (int j = 0; j < 8; ++j) v1[j] = 0.f;
    }

    uint4 o;
    unsigned* od = &o.x;
#pragma unroll
    for (int d = 0; d < 4; ++d) {
        int w = __builtin_amdgcn_cvt_pk_fp8_f32(v0[2*d]   - 0.5f, v1[2*d]   - 0.5f, 0, false);
        w = __builtin_amdgcn_cvt_pk_fp8_f32(v0[2*d+1] - 0.5f, v1[2*d+1] - 0.5f, w, true);
        od[d] = (unsigned)w;
    }
    *reinterpret_cast<uint4*>(pb + ((size_t)a * ASTR + (size_t)zb * ZSTR + (size_t)up * 16)) = o;
}

// ============ main: decoupled rings (geo slack 4, tap slack 6) ==============
struct __align__(8) G14 {
    float w0;       // weight of row i0; w1 = 1 - w0 (exact, so sum(w) == 120)
    unsigned boff;  // t*ASTR + (i0+27)*16
};

__global__ __launch_bounds__(192, 6) void bp_v14(const unsigned char* __restrict__ pb,
                                                 float* __restrict__ out) {
    __shared__ float2 s_cs[NA];
    __shared__ G14 s_geo[NA + 10][16]; // rows 120..129: pads (w0=0, boff=0)

    const int tid = threadIdx.x; // 0..191

    if (tid < NA) {
        const float ang = (float)tid * (float)(2.0 * M_PI / (double)NA);
        const float phi = (float)(1.5 * M_PI) - ang;
        s_cs[tid] = make_float2(cosf(phi), sinf(phi));
    }
    __syncthreads();

    // 2048 blocks; XCD-aware chunked swizzle (bijective: 2048 % 8 == 0).
    // swz bits: [10:4]=y (7b), [3:1]=xg (3b), [0]=zh (1b) — all consumed.
    const int bid = blockIdx.x;
    const int swz = (bid & 7) * 256 + (bid >> 3);
    const int y  = swz >> 4;              // 0..127
    const int xg = ((swz >> 1) & 7) << 4; // x base, step 16
    const int zh = swz & 1;               // z half: zb 0..11 or 12..23

    const float Y = (float)y - CTR;
    for (int e = tid; e < 16 * (NA + 10); e += 192) {
        const int p = e & 15;
        const int t = e >> 4;
        G14 g;
        if (t < NA) {
            const float2 cs = s_cs[t];
            const float X = (float)(xg + p) - CTR;
            const float u  = fmaf(cs.y, Y, fmaf(cs.x, X, CTR));
            const float fl = floorf(u);
            g.w0   = 1.0f - (u - fl);
            g.boff = (unsigned)(t * ASTR + ((int)fl + 27) * 16);
        } else {
            g.w0 = 0.f; g.boff = 0; // pad: loads land at pb[zbase], blend w=0
        }
        s_geo[t][p] = g;
    }
    __syncthreads();

    const int px = tid & 15;   // 16-px clusters read adjacent u (line sharing)
    const int zo = tid >> 4;   // 0..11
    const unsigned zbase = (unsigned)((zh * 12 + zo) * ZSTR);

    v2f acc[8];
#pragma unroll
    for (int j = 0; j < 8; ++j) acc[j] = (v2f){0.f, 0.f};

    // Two decoupled register rings:
    //   greg[4]: geo entries, ds_read issued 4 iterations before use
    //   T/wT[6]: taps + weight, global_load issued 6 iterations before use
    G14  greg[4];
    float wT[6];
    uint4 T[6];

#pragma unroll
    for (int j = 0; j < 6; ++j) { // taps for angles 0..5 (prologue: no slack)
        const G14 g = s_geo[j][px];
        wT[j] = g.w0;
        T[j] = *reinterpret_cast<const uint4*>(pb + (g.boff + zbase));
    }
#pragma unroll
    for (int j = 0; j < 4; ++j) { // geo for angles 6..9
        greg[j] = s_geo[6 + j][px];
    }

    // unroll 12 = lcm(6,4): all ring indices compile-time constants
    for (int t0 = 0; t0 < NA; t0 += 12) {
#pragma unroll
        for (int k = 0; k < 12; ++k) {
            const int sT = k % 6;
            const int sG = k % 4;
            // 1) blend angle t0+k (loaded 6 iterations ago)
            const uint4 cur = T[sT];
            const float cw0 = wT[sT];
            // 2) issue load for angle t0+k+6 (geo read 4 iterations ago)
            const G14 g = greg[sG];
            wT[sT] = g.w0;
            T[sT] = *reinterpret_cast<const uint4*>(pb + (g.boff + zbase));
            // 3) refill geo ring: angle t0+k+10 (consumed at iteration t0+k+4)
            greg[sG] = s_geo[t0 + k + 10][px];

            const v2f cw = {cw0, 1.0f - cw0};
            const unsigned* q = &cur.x;
#pragma unroll
            for (int d = 0; d < 4; ++d) {
                const v2f lo = __builtin_amdgcn_cvt_pk_f32_fp8((int)q[d], false); // (t0,t1) z=2d
                const v2f hi = __builtin_amdgcn_cvt_pk_f32_fp8((int)q[d], true);  // (t0,t1) z=2d+1
                pk_fma(acc[2*d + 0], cw, lo);
                pk_fma(acc[2*d + 1], cw, hi);
            }
        }
    }

    // out = (acc + 0.5 * sum(w)) / (120 + 1e-11); sum(w) == 120 exactly
    const float inv = (float)(1.0 / (120.0 + 1e-11));
    float* op = out + (size_t)(y * LR + xg + px) * LZ + (zh * 12 + zo) * 8;
    float4 r0, r1;
    r0.x = (acc[0][0] + acc[0][1] + 60.0f) * inv;
    r0.y = (acc[1][0] + acc[1][1] + 60.0f) * inv;
    r0.z = (acc[2][0] + acc[2][1] + 60.0f) * inv;
    r0.w = (acc[3][0] + acc[3][1] + 60.0f) * inv;
    r1.x = (acc[4][0] + acc[4][1] + 60.0f) * inv;
    r1.y = (acc[5][0] + acc[5][1] + 60.0f) * inv;
    r1.z = (acc[6][0] + acc[6][1] + 60.0f) * inv;
    r1.w = (acc[7][0] + acc[7][1] + 60.0f) * inv;
    *reinterpret_cast<float4*>(op)     = r0;
    *reinterpret_cast<float4*>(op + 4) = r1;
}

// ============ v5 fallback (smaller workspace): fp8 taps, 8 z/lane ===========
struct __align__(16) Geo {
    float w0, w1;
    int b0, b1;
};

__global__ __launch_bounds__(256) void cvt_fp8(const float* __restrict__ in,
                                               unsigned int* __restrict__ out8,
                                               int n16) {
    const int i = blockIdx.x * 256 + threadIdx.x;
    if (i >= n16) return;
    const float4* p = reinterpret_cast<const float4*>(in) + (size_t)i * 4;
    uint4 o;
    unsigned int* od = &o.x;
#pragma unroll
    for (int d = 0; d < 4; ++d) {
        const float4 f = p[d];
        int w = __builtin_amdgcn_cvt_pk_fp8_f32(f.x - 0.5f, f.y - 0.5f, 0, false);
        w = __builtin_amdgcn_cvt_pk_fp8_f32(f.z - 0.5f, f.w - 0.5f, w, true);
        od[d] = (unsigned int)w;
    }
    reinterpret_cast<uint4*>(out8)[i] = o;
}

__device__ inline void blend8(v2f acc[4], float w0, float w1,
                              const uint2& t0, const uint2& t1) {
    const v2f W0 = {w0, w0};
    const v2f W1 = {w1, w1};
    const unsigned int* q0 = &t0.x;
    const unsigned int* q1 = &t1.x;
#pragma unroll
    for (int d = 0; d < 2; ++d) {
        const v2f a_lo = __builtin_amdgcn_cvt_pk_f32_fp8((int)q0[d], false);
        const v2f a_hi = __builtin_amdgcn_cvt_pk_f32_fp8((int)q0[d], true);
        const v2f b_lo = __builtin_amdgcn_cvt_pk_f32_fp8((int)q1[d], false);
        const v2f b_hi = __builtin_amdgcn_cvt_pk_f32_fp8((int)q1[d], true);
        acc[2 * d + 0] = acc[2 * d + 0] + W0 * a_lo + W1 * b_lo;
        acc[2 * d + 1] = acc[2 * d + 1] + W0 * a_hi + W1 * b_hi;
    }
}

__global__ __launch_bounds__(192, 6) void bp_v5(const unsigned char* __restrict__ img,
                                                float* __restrict__ out) {
    __shared__ float2 s_cs[NA];
    __shared__ Geo s_geo[NA][8];
    __shared__ float s_sumw[8];

    const int tid = threadIdx.x;
    if (tid < NA) {
        const float ang = (float)tid * (float)(2.0 * M_PI / (double)NA);
        const float phi = (float)(1.5 * M_PI) - ang;
        s_cs[tid] = make_float2(cosf(phi), sinf(phi));
    }
    __syncthreads();

    const int bid = blockIdx.x;
    const int swz = (bid & 7) * 256 + (bid >> 3);
    const int y  = swz >> 4;
    const int xg = (swz & 15) << 3;

    const float Y = (float)y - CTR;
    for (int e = tid; e < 8 * NA; e += 192) {
        const int p = e & 7;
        const int a = e >> 3;
        const float2 cs = s_cs[a];
        const float X = (float)(xg + p) - CTR;
        const float u  = fmaf(cs.y, Y, fmaf(cs.x, X, CTR));
        const float fl = floorf(u);
        const float wx = u - fl;
        const int i0 = (int)fl;
        Geo g;
        g.w0 = ((unsigned)i0 < 128u) ? (1.0f - wx) : 0.0f;
        g.w1 = ((unsigned)(i0 + 1) < 128u) ? wx : 0.0f;
        const int o0 = min(max(i0, 0), LR - 1);
        const int o1 = min(max(i0 + 1, 0), LR - 1);
        g.b0 = (a * LR + o0) * LZ;
        g.b1 = (a * LR + o1) * LZ;
        s_geo[a][p] = g;
    }
    __syncthreads();

    if (tid < 8) {
        float s = 0.f;
        for (int a = 0; a < NA; ++a) s += s_geo[a][tid].w0 + s_geo[a][tid].w1;
        s_sumw[tid] = s;
    }
    __syncthreads();

    const int zo = tid % 24;
    const int px = tid / 24;
    const unsigned char* base = img + zo * 8;

    v2f acc[4];
#pragma unroll
    for (int j = 0; j < 4; ++j) acc[j] = (v2f){0.f, 0.f};

    Geo ga = s_geo[0][px];
    Geo gb = s_geo[1][px];
    uint2 A0 = *reinterpret_cast<const uint2*>(base + ga.b0);
    uint2 A1 = *reinterpret_cast<const uint2*>(base + ga.b1);
    uint2 B0 = *reinterpret_cast<const uint2*>(base + gb.b0);
    uint2 B1 = *reinterpret_cast<const uint2*>(base + gb.b1);

    for (int a = 0; a < NA - 2; a += 2) {
        const Geo gn = s_geo[a + 2][px];
        const uint2 N0 = *reinterpret_cast<const uint2*>(base + gn.b0);
        const uint2 N1 = *reinterpret_cast<const uint2*>(base + gn.b1);
        blend8(acc, ga.w0, ga.w1, A0, A1);
        ga = gn; A0 = N0; A1 = N1;
        const Geo gm = s_geo[a + 3][px];
        const uint2 M0 = *reinterpret_cast<const uint2*>(base + gm.b0);
        const uint2 M1 = *reinterpret_cast<const uint2*>(base + gm.b1);
        blend8(acc, gb.w0, gb.w1, B0, B1);
        gb = gm; B0 = M0; B1 = M1;
    }
    blend8(acc, ga.w0, ga.w1, A0, A1);
    blend8(acc, gb.w0, gb.w1, B0, B1);

    const float inv = (float)(1.0 / (120.0 + 1e-11));
    const float half_sw = 0.5f * s_sumw[px];
    float* op = out + ((size_t)(y * LR + xg + px)) * LZ + zo * 8;
    float4 r0, r1;
    r0.x = (acc[0][0] + half_sw) * inv;
    r0.y = (acc[0][1] + half_sw) * inv;
    r0.z = (acc[1][0] + half_sw) * inv;
    r0.w = (acc[1][1] + half_sw) * inv;
    r1.x = (acc[2][0] + half_sw) * inv;
    r1.y = (acc[2][1] + half_sw) * inv;
    r1.z = (acc[3][0] + half_sw) * inv;
    r1.w = (acc[3][1] + half_sw) * inv;
    *reinterpret_cast<float4*>(op)     = r0;
    *reinterpret_cast<float4*>(op + 4) = r1;
}

// ============ fp32 fallback (no workspace) ==================================
__global__ __launch_bounds__(192) void bp_main(const float* __restrict__ img,
                                               float* __restrict__ out) {
    __shared__ float s_cp[NA];
    __shared__ float s_sp[NA];
    struct __align__(16) GeoF { float w0, w1; int off0, off1; };
    __shared__ GeoF s_geo[4][NA];

    const int tx = threadIdx.x;
    const int py = threadIdx.y;
    const int tid = py * 48 + tx;
    const int y  = blockIdx.x >> 5;
    const int xg = (blockIdx.x & 31) << 2;

    if (tid < NA) {
        const float ang = (float)tid * (float)(2.0 * M_PI / (double)NA);
        const float phi = (float)(1.5 * M_PI) - ang;
        s_cp[tid] = cosf(phi);
        s_sp[tid] = sinf(phi);
    }
    __syncthreads();

    for (int e = tid; e < 4 * NA; e += 192) {
        const int a = e % NA;
        const int p = e / NA;
        const float cp = s_cp[a];
        const float sp = s_sp[a];
        const float Yf = (float)y - CTR;
        const float Xf = (float)(xg + p) - CTR;
        const float u = sp * Yf + cp * Xf + CTR;
        const float fl = floorf(u);
        const float wx = u - fl;
        const int i0 = (int)fl;
        GeoF g;
        g.w0 = (i0 >= 0 && i0 < LR) ? (1.0f - wx) : 0.0f;
        g.w1 = (i0 >= -1 && i0 < LR - 1) ? wx : 0.0f;
        const int o0 = min(max(i0, 0), LR - 1);
        const int o1 = min(max(i0 + 1, 0), LR - 1);
        g.off0 = (a * LR + o0) * LZ;
        g.off1 = (a * LR + o1) * LZ;
        s_geo[p][a] = g;
    }
    __syncthreads();

    const int zb = tx << 2;
    float4 acc = make_float4(0.f, 0.f, 0.f, 0.f);
#pragma unroll 4
    for (int a = 0; a < NA; ++a) {
        const GeoF g = s_geo[py][a];
        const float4 v0 = *reinterpret_cast<const float4*>(img + g.off0 + zb);
        const float4 v1 = *reinterpret_cast<const float4*>(img + g.off1 + zb);
        acc.x = fmaf(g.w0, v0.x, fmaf(g.w1, v1.x, acc.x));
        acc.y = fmaf(g.w0, v0.y, fmaf(g.w1, v1.y, acc.y));
        acc.z = fmaf(g.w0, v0.z, fmaf(g.w1, v1.z, acc.z));
        acc.w = fmaf(g.w0, v0.w, fmaf(g.w1, v1.w, acc.w));
    }
    const float inv = (float)(1.0 / (120.0 + 1e-11));
    float4 r;
    r.x = acc.x * inv; r.y = acc.y * inv; r.z = acc.z * inv; r.w = acc.w * inv;
    *reinterpret_cast<float4*>(out + (y * LR + xg + py) * LZ + zb) = r;
}

} // namespace

extern "C" void kernel_launch(void* const* d_in, const int* in_sizes, int n_in,
                              void* d_out, int out_size, void* d_ws, size_t ws_size,
                              hipStream_t stream) {
    const float* img = (const float*)d_in[0];
    float* out = (float*)d_out;
    const int n = NA * LR * LZ;                        // 2,949,120
    const size_t v14_bytes = (size_t)NA * ASTR;        // 8,386,560
    const size_t fp8_bytes = (size_t)n;                // 2,949,120

    if (ws_size >= v14_bytes) {
        unsigned char* pb = (unsigned char*)d_ws;
        const int nt = NA * UW2 * 24;                  // 524,160
        hipLaunchKernelGGL(cvt9, dim3((nt + 255) / 256), dim3(256), 0, stream,
                           img, pb);
        hipLaunchKernelGGL(bp_v14, dim3(2048), dim3(192), 0, stream, pb, out);
    } else if (ws_size >= fp8_bytes) {
        unsigned int* img8 = (unsigned int*)d_ws;
        const int n16 = n / 16;
        hipLaunchKernelGGL(cvt_fp8, dim3((n16 + 255) / 256), dim3(256), 0, stream,
                           img, img8, n16);
        hipLaunchKernelGGL(bp_v5, dim3(128 * 16), dim3(192), 0, stream,
                           (const unsigned char*)img8, out);
    } else {
        hipLaunchKernelGGL(bp_main, dim3(128 * 32), dim3(48, 4), 0, stream,
                           img, out);
    }
}

// Round 15
// 48.864 us; speedup vs baseline: 1.6918x; 1.0160x over previous
//
#include <hip/hip_runtime.h>
#include <math.h>

namespace {

constexpr int NA = 120;
constexpr int LR = 128;
constexpr int LZ = 192;
constexpr int UW2 = 182;          // u' rows 0..181 (u' = i0 + 27, i0 in [-27,154])
constexpr int ZSTR = UW2 * 16;    // 2912 B per zb step
constexpr int ASTR = 24 * ZSTR;   // 69888 B per angle slab
constexpr float CTR = 63.5f;      // unpadded-space center

typedef float v2f __attribute__((ext_vector_type(2)));
typedef _Float16 half_t;
typedef half_t v2h __attribute__((ext_vector_type(2)));

#if defined(__has_builtin)
#if __has_builtin(__builtin_amdgcn_cvt_scalef32_pk_f16_fp8) && __has_builtin(__builtin_amdgcn_fdot2)
#define USE_DOT2 1
#endif
#endif

__device__ inline void pk_fma(v2f& acc, v2f w, v2f t) {
    asm("v_pk_fma_f32 %0, %1, %2, %0" : "+v"(acc) : "v"(w), "v"(t));
}

// ============ pre-pass: zb-major fp8 PAIR buffer ============================
// Entry (a, zb, u') = 16 B: interleaved fp8 pairs (row u'-27, row u'-26) for
// z in [8*zb, 8*zb+8), values stored centered (v - 0.5). Out-of-range rows
// (zero-pad region) store fp8(-0.5) -> no masks in the main loop.
__global__ __launch_bounds__(256) void cvt9(const float* __restrict__ img,
                                            unsigned char* __restrict__ pb) {
    const int idx = blockIdx.x * 256 + threadIdx.x;
    if (idx >= NA * UW2 * 24) return; // 524,160
    const int up = idx % UW2;
    const int t  = idx / UW2;
    const int zb = t % 24;
    const int a  = t / 24;
    const int z0 = zb * 8;
    const int r0 = up - 27;
    const int r1 = up - 26;

    float v0[8], v1[8];
    if (r0 >= 0 && r0 < LR) {
        const float4* p = reinterpret_cast<const float4*>(img + (a * LR + r0) * LZ + z0);
        const float4 x = p[0], y = p[1];
        v0[0]=x.x; v0[1]=x.y; v0[2]=x.z; v0[3]=x.w;
        v0[4]=y.x; v0[5]=y.y; v0[6]=y.z; v0[7]=y.w;
    } else {
#pragma unroll
        for (int j = 0; j < 8; ++j) v0[j] = 0.f;
    }
    if (r1 >= 0 && r1 < LR) {
        const float4* p = reinterpret_cast<const float4*>(img + (a * LR + r1) * LZ + z0);
        const float4 x = p[0], y = p[1];
        v1[0]=x.x; v1[1]=x.y; v1[2]=x.z; v1[3]=x.w;
        v1[4]=y.x; v1[5]=y.y; v1[6]=y.z; v1[7]=y.w;
    } else {
#pragma unroll
        for (int j = 0; j < 8; ++j) v1[j] = 0.f;
    }

    uint4 o;
    unsigned* od = &o.x;
#pragma unroll
    for (int d = 0; d < 4; ++d) {
        int w = __builtin_amdgcn_cvt_pk_fp8_f32(v0[2*d]   - 0.5f, v1[2*d]   - 0.5f, 0, false);
        w = __builtin_amdgcn_cvt_pk_fp8_f32(v0[2*d+1] - 0.5f, v1[2*d+1] - 0.5f, w, true);
        od[d] = (unsigned)w;
    }
    *reinterpret_cast<uint4*>(pb + ((size_t)a * ASTR + (size_t)zb * ZSTR + (size_t)up * 16)) = o;
}

// ============ main: v14 rings + f16-dot2 blend (fallback: v14 exact) ========
struct __align__(8) G15 {
    unsigned w;     // USE_DOT2: packed v2h (w0,w1); else: f32 bits of w0
    unsigned boff;  // t*ASTR + (i0+27)*16
};

__global__ __launch_bounds__(192, 6) void bp_v15(const unsigned char* __restrict__ pb,
                                                 float* __restrict__ out) {
    __shared__ float2 s_cs[NA];
    __shared__ G15 s_geo[NA + 10][16]; // rows 120..129: pads (w=0, boff=0)

    const int tid = threadIdx.x; // 0..191

    if (tid < NA) {
        const float ang = (float)tid * (float)(2.0 * M_PI / (double)NA);
        const float phi = (float)(1.5 * M_PI) - ang;
        s_cs[tid] = make_float2(cosf(phi), sinf(phi));
    }
    __syncthreads();

    // 2048 blocks; XCD-aware chunked swizzle (bijective: 2048 % 8 == 0).
    const int bid = blockIdx.x;
    const int swz = (bid & 7) * 256 + (bid >> 3);
    const int y  = swz >> 4;              // 0..127
    const int xg = ((swz >> 1) & 7) << 4; // x base, step 16
    const int zh = swz & 1;               // z half: zb 0..11 or 12..23

    const float Y = (float)y - CTR;
    for (int e = tid; e < 16 * (NA + 10); e += 192) {
        const int p = e & 15;
        const int t = e >> 4;
        G15 g;
        if (t < NA) {
            const float2 cs = s_cs[t];
            const float X = (float)(xg + p) - CTR;
            const float u  = fmaf(cs.y, Y, fmaf(cs.x, X, CTR));
            const float fl = floorf(u);
            const float wx = u - fl;
#ifdef USE_DOT2
            union { v2h h; unsigned u32; } cw;
            cw.h = (v2h){(half_t)(1.0f - wx), (half_t)wx};
            g.w = cw.u32;
#else
            g.w = __float_as_uint(1.0f - wx);
#endif
            g.boff = (unsigned)(t * ASTR + ((int)fl + 27) * 16);
        } else {
            g.w = 0u; g.boff = 0; // pad: loads land at pb[zbase], blend w=0
        }
        s_geo[t][p] = g;
    }
    __syncthreads();

    const int px = tid & 15;
    const int zo = tid >> 4;   // 0..11
    const unsigned zbase = (unsigned)((zh * 12 + zo) * ZSTR);

#ifdef USE_DOT2
    float fac[8];
#pragma unroll
    for (int j = 0; j < 8; ++j) fac[j] = 0.f;
#else
    v2f acc[8];
#pragma unroll
    for (int j = 0; j < 8; ++j) acc[j] = (v2f){0.f, 0.f};
#endif

    // Two decoupled register rings (v14): geo slack 4, tap slack 6.
    G15  greg[4];
    unsigned wT[6];
    uint4 T[6];

#pragma unroll
    for (int j = 0; j < 6; ++j) {
        const G15 g = s_geo[j][px];
        wT[j] = g.w;
        T[j] = *reinterpret_cast<const uint4*>(pb + (g.boff + zbase));
    }
#pragma unroll
    for (int j = 0; j < 4; ++j) {
        greg[j] = s_geo[6 + j][px];
    }

    for (int t0 = 0; t0 < NA; t0 += 12) {
#pragma unroll
        for (int k = 0; k < 12; ++k) {
            const int sT = k % 6;
            const int sG = k % 4;
            const uint4 cur = T[sT];
            const unsigned cwb = wT[sT];
            const G15 g = greg[sG];
            wT[sT] = g.w;
            T[sT] = *reinterpret_cast<const uint4*>(pb + (g.boff + zbase));
            greg[sG] = s_geo[t0 + k + 10][px];

            const unsigned* q = &cur.x;
#ifdef USE_DOT2
            union { unsigned u32; v2h h; } cw;
            cw.u32 = cwb;
#pragma unroll
            for (int d = 0; d < 4; ++d) {
                // dword d bytes: (t0 z=2d, t1 z=2d, t0 z=2d+1, t1 z=2d+1)
                const v2h lo = __builtin_amdgcn_cvt_scalef32_pk_f16_fp8((int)q[d], 1.0f, false);
                const v2h hi = __builtin_amdgcn_cvt_scalef32_pk_f16_fp8((int)q[d], 1.0f, true);
                fac[2*d + 0] = __builtin_amdgcn_fdot2(cw.h, lo, fac[2*d + 0], false);
                fac[2*d + 1] = __builtin_amdgcn_fdot2(cw.h, hi, fac[2*d + 1], false);
            }
#else
            const float cw0 = __uint_as_float(cwb);
            const v2f cwv = {cw0, 1.0f - cw0};
#pragma unroll
            for (int d = 0; d < 4; ++d) {
                const v2f lo = __builtin_amdgcn_cvt_pk_f32_fp8((int)q[d], false);
                const v2f hi = __builtin_amdgcn_cvt_pk_f32_fp8((int)q[d], true);
                pk_fma(acc[2*d + 0], cwv, lo);
                pk_fma(acc[2*d + 1], cwv, hi);
            }
#endif
        }
    }

    // out = (acc + 0.5 * sum(w)) / (120 + 1e-11); sum(w) == 120 (w1 = 1-w0)
    const float inv = (float)(1.0 / (120.0 + 1e-11));
    float* op = out + (size_t)(y * LR + xg + px) * LZ + (zh * 12 + zo) * 8;
    float4 r0, r1;
#ifdef USE_DOT2
    r0.x = (fac[0] + 60.0f) * inv;
    r0.y = (fac[1] + 60.0f) * inv;
    r0.z = (fac[2] + 60.0f) * inv;
    r0.w = (fac[3] + 60.0f) * inv;
    r1.x = (fac[4] + 60.0f) * inv;
    r1.y = (fac[5] + 60.0f) * inv;
    r1.z = (fac[6] + 60.0f) * inv;
    r1.w = (fac[7] + 60.0f) * inv;
#else
    r0.x = (acc[0][0] + acc[0][1] + 60.0f) * inv;
    r0.y = (acc[1][0] + acc[1][1] + 60.0f) * inv;
    r0.z = (acc[2][0] + acc[2][1] + 60.0f) * inv;
    r0.w = (acc[3][0] + acc[3][1] + 60.0f) * inv;
    r1.x = (acc[4][0] + acc[4][1] + 60.0f) * inv;
    r1.y = (acc[5][0] + acc[5][1] + 60.0f) * inv;
    r1.z = (acc[6][0] + acc[6][1] + 60.0f) * inv;
    r1.w = (acc[7][0] + acc[7][1] + 60.0f) * inv;
#endif
    *reinterpret_cast<float4*>(op)     = r0;
    *reinterpret_cast<float4*>(op + 4) = r1;
}

// ============ v5 fallback (smaller workspace): fp8 taps, 8 z/lane ===========
struct __align__(16) Geo {
    float w0, w1;
    int b0, b1;
};

__global__ __launch_bounds__(256) void cvt_fp8(const float* __restrict__ in,
                                               unsigned int* __restrict__ out8,
                                               int n16) {
    const int i = blockIdx.x * 256 + threadIdx.x;
    if (i >= n16) return;
    const float4* p = reinterpret_cast<const float4*>(in) + (size_t)i * 4;
    uint4 o;
    unsigned int* od = &o.x;
#pragma unroll
    for (int d = 0; d < 4; ++d) {
        const float4 f = p[d];
        int w = __builtin_amdgcn_cvt_pk_fp8_f32(f.x - 0.5f, f.y - 0.5f, 0, false);
        w = __builtin_amdgcn_cvt_pk_fp8_f32(f.z - 0.5f, f.w - 0.5f, w, true);
        od[d] = (unsigned int)w;
    }
    reinterpret_cast<uint4*>(out8)[i] = o;
}

__device__ inline void blend8(v2f acc[4], float w0, float w1,
                              const uint2& t0, const uint2& t1) {
    const v2f W0 = {w0, w0};
    const v2f W1 = {w1, w1};
    const unsigned int* q0 = &t0.x;
    const unsigned int* q1 = &t1.x;
#pragma unroll
    for (int d = 0; d < 2; ++d) {
        const v2f a_lo = __builtin_amdgcn_cvt_pk_f32_fp8((int)q0[d], false);
        const v2f a_hi = __builtin_amdgcn_cvt_pk_f32_fp8((int)q0[d], true);
        const v2f b_lo = __builtin_amdgcn_cvt_pk_f32_fp8((int)q1[d], false);
        const v2f b_hi = __builtin_amdgcn_cvt_pk_f32_fp8((int)q1[d], true);
        acc[2 * d + 0] = acc[2 * d + 0] + W0 * a_lo + W1 * b_lo;
        acc[2 * d + 1] = acc[2 * d + 1] + W0 * a_hi + W1 * b_hi;
    }
}

__global__ __launch_bounds__(192, 6) void bp_v5(const unsigned char* __restrict__ img,
                                                float* __restrict__ out) {
    __shared__ float2 s_cs[NA];
    __shared__ Geo s_geo[NA][8];
    __shared__ float s_sumw[8];

    const int tid = threadIdx.x;
    if (tid < NA) {
        const float ang = (float)tid * (float)(2.0 * M_PI / (double)NA);
        const float phi = (float)(1.5 * M_PI) - ang;
        s_cs[tid] = make_float2(cosf(phi), sinf(phi));
    }
    __syncthreads();

    const int bid = blockIdx.x;
    const int swz = (bid & 7) * 256 + (bid >> 3);
    const int y  = swz >> 4;
    const int xg = (swz & 15) << 3;

    const float Y = (float)y - CTR;
    for (int e = tid; e < 8 * NA; e += 192) {
        const int p = e & 7;
        const int a = e >> 3;
        const float2 cs = s_cs[a];
        const float X = (float)(xg + p) - CTR;
        const float u  = fmaf(cs.y, Y, fmaf(cs.x, X, CTR));
        const float fl = floorf(u);
        const float wx = u - fl;
        const int i0 = (int)fl;
        Geo g;
        g.w0 = ((unsigned)i0 < 128u) ? (1.0f - wx) : 0.0f;
        g.w1 = ((unsigned)(i0 + 1) < 128u) ? wx : 0.0f;
        const int o0 = min(max(i0, 0), LR - 1);
        const int o1 = min(max(i0 + 1, 0), LR - 1);
        g.b0 = (a * LR + o0) * LZ;
        g.b1 = (a * LR + o1) * LZ;
        s_geo[a][p] = g;
    }
    __syncthreads();

    if (tid < 8) {
        float s = 0.f;
        for (int a = 0; a < NA; ++a) s += s_geo[a][tid].w0 + s_geo[a][tid].w1;
        s_sumw[tid] = s;
    }
    __syncthreads();

    const int zo = tid % 24;
    const int px = tid / 24;
    const unsigned char* base = img + zo * 8;

    v2f acc[4];
#pragma unroll
    for (int j = 0; j < 4; ++j) acc[j] = (v2f){0.f, 0.f};

    Geo ga = s_geo[0][px];
    Geo gb = s_geo[1][px];
    uint2 A0 = *reinterpret_cast<const uint2*>(base + ga.b0);
    uint2 A1 = *reinterpret_cast<const uint2*>(base + ga.b1);
    uint2 B0 = *reinterpret_cast<const uint2*>(base + gb.b0);
    uint2 B1 = *reinterpret_cast<const uint2*>(base + gb.b1);

    for (int a = 0; a < NA - 2; a += 2) {
        const Geo gn = s_geo[a + 2][px];
        const uint2 N0 = *reinterpret_cast<const uint2*>(base + gn.b0);
        const uint2 N1 = *reinterpret_cast<const uint2*>(base + gn.b1);
        blend8(acc, ga.w0, ga.w1, A0, A1);
        ga = gn; A0 = N0; A1 = N1;
        const Geo gm = s_geo[a + 3][px];
        const uint2 M0 = *reinterpret_cast<const uint2*>(base + gm.b0);
        const uint2 M1 = *reinterpret_cast<const uint2*>(base + gm.b1);
        blend8(acc, gb.w0, gb.w1, B0, B1);
        gb = gm; B0 = M0; B1 = M1;
    }
    blend8(acc, ga.w0, ga.w1, A0, A1);
    blend8(acc, gb.w0, gb.w1, B0, B1);

    const float inv = (float)(1.0 / (120.0 + 1e-11));
    const float half_sw = 0.5f * s_sumw[px];
    float* op = out + ((size_t)(y * LR + xg + px)) * LZ + zo * 8;
    float4 r0, r1;
    r0.x = (acc[0][0] + half_sw) * inv;
    r0.y = (acc[0][1] + half_sw) * inv;
    r0.z = (acc[1][0] + half_sw) * inv;
    r0.w = (acc[1][1] + half_sw) * inv;
    r1.x = (acc[2][0] + half_sw) * inv;
    r1.y = (acc[2][1] + half_sw) * inv;
    r1.z = (acc[3][0] + half_sw) * inv;
    r1.w = (acc[3][1] + half_sw) * inv;
    *reinterpret_cast<float4*>(op)     = r0;
    *reinterpret_cast<float4*>(op + 4) = r1;
}

// ============ fp32 fallback (no workspace) ==================================
__global__ __launch_bounds__(192) void bp_main(const float* __restrict__ img,
                                               float* __restrict__ out) {
    __shared__ float s_cp[NA];
    __shared__ float s_sp[NA];
    struct __align__(16) GeoF { float w0, w1; int off0, off1; };
    __shared__ GeoF s_geo[4][NA];

    const int tx = threadIdx.x;
    const int py = threadIdx.y;
    const int tid = py * 48 + tx;
    const int y  = blockIdx.x >> 5;
    const int xg = (blockIdx.x & 31) << 2;

    if (tid < NA) {
        const float ang = (float)tid * (float)(2.0 * M_PI / (double)NA);
        const float phi = (float)(1.5 * M_PI) - ang;
        s_cp[tid] = cosf(phi);
        s_sp[tid] = sinf(phi);
    }
    __syncthreads();

    for (int e = tid; e < 4 * NA; e += 192) {
        const int a = e % NA;
        const int p = e / NA;
        const float cp = s_cp[a];
        const float sp = s_sp[a];
        const float Yf = (float)y - CTR;
        const float Xf = (float)(xg + p) - CTR;
        const float u = sp * Yf + cp * Xf + CTR;
        const float fl = floorf(u);
        const float wx = u - fl;
        const int i0 = (int)fl;
        GeoF g;
        g.w0 = (i0 >= 0 && i0 < LR) ? (1.0f - wx) : 0.0f;
        g.w1 = (i0 >= -1 && i0 < LR - 1) ? wx : 0.0f;
        const int o0 = min(max(i0, 0), LR - 1);
        const int o1 = min(max(i0 + 1, 0), LR - 1);
        g.off0 = (a * LR + o0) * LZ;
        g.off1 = (a * LR + o1) * LZ;
        s_geo[p][a] = g;
    }
    __syncthreads();

    const int zb = tx << 2;
    float4 acc = make_float4(0.f, 0.f, 0.f, 0.f);
#pragma unroll 4
    for (int a = 0; a < NA; ++a) {
        const GeoF g = s_geo[py][a];
        const float4 v0 = *reinterpret_cast<const float4*>(img + g.off0 + zb);
        const float4 v1 = *reinterpret_cast<const float4*>(img + g.off1 + zb);
        acc.x = fmaf(g.w0, v0.x, fmaf(g.w1, v1.x, acc.x));
        acc.y = fmaf(g.w0, v0.y, fmaf(g.w1, v1.y, acc.y));
        acc.z = fmaf(g.w0, v0.z, fmaf(g.w1, v1.z, acc.z));
        acc.w = fmaf(g.w0, v0.w, fmaf(g.w1, v1.w, acc.w));
    }
    const float inv = (float)(1.0 / (120.0 + 1e-11));
    float4 r;
    r.x = acc.x * inv; r.y = acc.y * inv; r.z = acc.z * inv; r.w = acc.w * inv;
    *reinterpret_cast<float4*>(out + (y * LR + xg + py) * LZ + zb) = r;
}

} // namespace

extern "C" void kernel_launch(void* const* d_in, const int* in_sizes, int n_in,
                              void* d_out, int out_size, void* d_ws, size_t ws_size,
                              hipStream_t stream) {
    const float* img = (const float*)d_in[0];
    float* out = (float*)d_out;
    const int n = NA * LR * LZ;                        // 2,949,120
    const size_t v15_bytes = (size_t)NA * ASTR;        // 8,386,560
    const size_t fp8_bytes = (size_t)n;                // 2,949,120

    if (ws_size >= v15_bytes) {
        unsigned char* pb = (unsigned char*)d_ws;
        const int nt = NA * UW2 * 24;                  // 524,160
        hipLaunchKernelGGL(cvt9, dim3((nt + 255) / 256), dim3(256), 0, stream,
                           img, pb);
        hipLaunchKernelGGL(bp_v15, dim3(2048), dim3(192), 0, stream, pb, out);
    } else if (ws_size >= fp8_bytes) {
        unsigned int* img8 = (unsigned int*)d_ws;
        const int n16 = n / 16;
        hipLaunchKernelGGL(cvt_fp8, dim3((n16 + 255) / 256), dim3(256), 0, stream,
                           img, img8, n16);
        hipLaunchKernelGGL(bp_v5, dim3(128 * 16), dim3(192), 0, stream,
                           (const unsigned char*)img8, out);
    } else {
        hipLaunchKernelGGL(bp_main, dim3(128 * 32), dim3(48, 4), 0, stream,
                           img, out);
    }
}